// Round 7
// baseline (316.722 us; speedup 1.0000x reference)
//
#include <hip/hip_runtime.h>
#include <math.h>

#define BB 32
#define LL 512
#define DM 128
#define DI 256
#define DSN 16
#define NMK 4
#define NC 16
#define CL 32   // LL/NC

__device__ __forceinline__ float silu_f(float x){ return x / (1.f + __expf(-x)); }

// ---------------- 1. per-batch normalization ----------------
__global__ void norm_kernel(const float* __restrict__ x_enc,
                            float* __restrict__ xn, float* __restrict__ stats){
  __shared__ float xs[LL];
  __shared__ float red[256];
  int b = blockIdx.x, t = threadIdx.x;
  xs[t]       = x_enc[b*LL + t];
  xs[t + 256] = x_enc[b*LL + t + 256];
  __syncthreads();
  red[t] = xs[t] + xs[t + 256];
  __syncthreads();
  for (int s = 128; s; s >>= 1){ if (t < s) red[t] += red[t + s]; __syncthreads(); }
  float mean = red[0] / (float)LL;
  __syncthreads();
  float xc0 = xs[t] - mean, xc1 = xs[t + 256] - mean;
  red[t] = xc0*xc0 + xc1*xc1;
  __syncthreads();
  for (int s = 128; s; s >>= 1){ if (t < s) red[t] += red[t + s]; __syncthreads(); }
  float var = red[0] / (float)LL;
  float sd = sqrtf(var + 1e-5f);
  xn[b*LL + t]       = xc0 / sd;
  xn[b*LL + t + 256] = xc1 / sd;
  if (t == 0){ stats[b] = mean; stats[BB + b] = sd; }
}

// ---------------- 2. token conv + temporal + positional embedding ----------------
__global__ void embed_kernel(const float* __restrict__ xn, const float* __restrict__ xmark,
                             const float* __restrict__ tok_w, const float* __restrict__ temp_w,
                             float* __restrict__ xbuf){
  int row = blockIdx.x;          // b*LL + l
  int o = threadIdx.x;           // 0..127
  int b = row >> 9, l = row & 511;
  float xm1 = xn[b*LL + ((l == 0) ? (LL - 1) : (l - 1))];
  float x0  = xn[row];
  float xp1 = xn[b*LL + ((l == LL - 1) ? 0 : (l + 1))];
  float v = xm1 * tok_w[o*3 + 0] + x0 * tok_w[o*3 + 1] + xp1 * tok_w[o*3 + 2];
  #pragma unroll
  for (int m = 0; m < NMK; ++m) v += xmark[row*NMK + m] * temp_w[m*DM + o];
  int i = o >> 1;
  float ang = (float)l * expf((float)(2*i) * -0.07195578415606394f); // -ln(10000)/128
  v += (o & 1) ? cosf(ang) : sinf(ang);
  xbuf[row*DM + o] = v;
}

// ---------------- 3. in_proj GEMM 64x64 tile; epilogue splits xi / silu(z) ----------------
template<int MODE>
__global__ __launch_bounds__(256) void gemm64_kernel(const float* __restrict__ A,
    const float* __restrict__ W, float* __restrict__ out0, float* __restrict__ out1,
    int M, int N, int K){
  __shared__ float AsT[32][68];
  __shared__ float Bs[32][64];
  int tid = threadIdx.x;
  int tx = tid & 15, ty = tid >> 4;
  int rowBase = blockIdx.x * 64, colBase = blockIdx.y * 64;
  float acc[4][4] = {};
  for (int kc = 0; kc < K; kc += 32){
    #pragma unroll
    for (int i = 0; i < 8; ++i){
      int idx = tid + i*256;
      int r = idx >> 5, k = idx & 31;
      AsT[k][r] = A[(size_t)(rowBase + r)*K + kc + k];
    }
    #pragma unroll
    for (int i = 0; i < 8; ++i){
      int idx = tid + i*256;
      int k = idx >> 6, c = idx & 63;
      Bs[k][c] = W[(size_t)(kc + k)*N + colBase + c];
    }
    __syncthreads();
    #pragma unroll
    for (int k = 0; k < 32; ++k){
      float4 a  = *(const float4*)&AsT[k][ty*4];
      float4 bv = *(const float4*)&Bs[k][tx*4];
      float av[4] = {a.x, a.y, a.z, a.w};
      float bb[4] = {bv.x, bv.y, bv.z, bv.w};
      #pragma unroll
      for (int ii = 0; ii < 4; ++ii)
        #pragma unroll
        for (int jj = 0; jj < 4; ++jj) acc[ii][jj] += av[ii]*bb[jj];
    }
    __syncthreads();
  }
  #pragma unroll
  for (int ii = 0; ii < 4; ++ii){
    int row = rowBase + ty*4 + ii;
    #pragma unroll
    for (int jj = 0; jj < 4; ++jj){
      int col = colBase + tx*4 + jj;
      float v = acc[ii][jj];
      if (MODE == 0){
        out0[(size_t)row*N + col] = v;
      } else {
        if (col < DI) out0[(size_t)row*DI + col] = v;
        else          out1[(size_t)row*DI + col - DI] = silu_f(v);
      }
    }
  }
}

// ---------------- 4. depthwise causal conv + silu ----------------
__global__ void conv_kernel(const float* __restrict__ xi_raw, const float* __restrict__ conv_w,
                            const float* __restrict__ conv_b, float* __restrict__ xi2){
  int row = blockIdx.x, d = threadIdx.x;
  int l = row & 511;
  float acc = conv_b[d];
  #pragma unroll
  for (int k = 0; k < 4; ++k){
    int t = l + k - 3;
    if (t >= 0) acc += xi_raw[(size_t)(row + k - 3)*DI + d] * conv_w[d*4 + k];
  }
  xi2[(size_t)row*DI + d] = silu_f(acc);
}

// ---------------- 5. dbl GEMM (N=40) + fused dt/softplus + transposed outputs ----------------
// 32-row tiles -> 512 blocks. Writes BT/CT [b][n][l], dtT/xiT [b][d][l].
__global__ __launch_bounds__(256) void dbl_kernel(const float* __restrict__ xi2,
    const float* __restrict__ xpw, const float* __restrict__ dt_w,
    const float* __restrict__ dt_b, float* __restrict__ BT,
    float* __restrict__ CT, float* __restrict__ dtT, float* __restrict__ xiT){
  __shared__ float Xs[64][33];    // [k][row]
  __shared__ float Ws[64][48];    // [k][col], 40 padded to 48
  __shared__ float rowp8[32][8];
  int t = threadIdx.x;
  int r = t >> 3, g = t & 7;      // row 0..31, colgroup 0..7 (6 cols each)
  int rowBase = blockIdx.x * 32;
  float acc[6] = {};
  for (int kc = 0; kc < DI; kc += 64){
    #pragma unroll
    for (int i = 0; i < 8; ++i){
      int idx = t + i*256;
      int rr = idx >> 6, k = idx & 63;
      Xs[k][rr] = xi2[(size_t)(rowBase + rr)*DI + kc + k];
    }
    #pragma unroll
    for (int i = 0; i < 12; ++i){
      int idx = t + i*256;
      int k = idx / 48, j = idx % 48;
      Ws[k][j] = (j < 40) ? xpw[(kc + k)*40 + j] : 0.f;
    }
    __syncthreads();
    #pragma unroll 8
    for (int k = 0; k < 64; ++k){
      float a = Xs[k][r];
      const float2* wr = (const float2*)&Ws[k][g*6];
      float2 w0 = wr[0], w1 = wr[1], w2 = wr[2];
      acc[0] += a*w0.x; acc[1] += a*w0.y;
      acc[2] += a*w1.x; acc[3] += a*w1.y;
      acc[4] += a*w2.x; acc[5] += a*w2.y;
    }
    __syncthreads();
  }
  size_t row = rowBase + r;
  int b = (int)(row >> 9), l = (int)(row & 511);
  #pragma unroll
  for (int jj = 0; jj < 6; ++jj){
    int j = g*6 + jj;
    if (j < 8)       rowp8[r][j] = acc[jj];
    else if (j < 24) BT[((size_t)b*DSN + (j - 8))*LL + l]  = acc[jj];
    else if (j < 40) CT[((size_t)b*DSN + (j - 24))*LL + l] = acc[jj];
  }
  __syncthreads();
  // dt + transpose phase: thread t = channel d; 32 l-values in registers -> float4 stores
  int b2 = rowBase >> 9;
  int l0 = rowBase & 511;
  float dtw_l[8];
  #pragma unroll
  for (int q = 0; q < 8; ++q) dtw_l[q] = dt_w[q*DI + t];
  float dtb_l = dt_b[t];
  // batch-issue the 32 xi loads
  float xiL[32];
  #pragma unroll
  for (int rr = 0; rr < 32; ++rr) xiL[rr] = xi2[(size_t)(rowBase + rr)*DI + t];
  float* pdt = dtT + ((size_t)b2*DI + t)*LL + l0;
  float* pxi = xiT + ((size_t)b2*DI + t)*LL + l0;
  #pragma unroll
  for (int g4 = 0; g4 < 8; ++g4){
    float4 d4, x4;
    float dv[4];
    #pragma unroll
    for (int i = 0; i < 4; ++i){
      int rr = g4*4 + i;
      float dtp = dtb_l;
      #pragma unroll
      for (int q = 0; q < 8; ++q) dtp += rowp8[rr][q] * dtw_l[q];
      dv[i] = fmaxf(dtp, 0.f) + log1pf(__expf(-fabsf(dtp)));
    }
    d4.x = dv[0]; d4.y = dv[1]; d4.z = dv[2]; d4.w = dv[3];
    x4.x = xiL[g4*4]; x4.y = xiL[g4*4+1]; x4.z = xiL[g4*4+2]; x4.w = xiL[g4*4+3];
    *(float4*)(pdt + g4*4) = d4;
    *(float4*)(pxi + g4*4) = x4;
  }
}

// ---------------- 6a. chunk-local scan: float4-streamed ----------------
// grid (BB, DI/16, NC), block 256 = 16 d x 16 n
__global__ __launch_bounds__(256) void scan_part1_kernel(const float* __restrict__ dtT,
    const float* __restrict__ xiT, const float* __restrict__ BT,
    const float* __restrict__ A_log, float* __restrict__ hend, float* __restrict__ Pprod){
  int t = threadIdx.x;
  int n = t & 15, dl = t >> 4;
  int d = blockIdx.y * 16 + dl;
  int b = blockIdx.x, j = blockIdx.z;
  float A = -__expf(A_log[d*DSN + n]);
  int l0 = j * CL;
  const float4* pdt = (const float4*)(dtT + ((size_t)b*DI + d)*LL + l0);
  const float4* pxi = (const float4*)(xiT + ((size_t)b*DI + d)*LL + l0);
  const float4* pB  = (const float4*)(BT  + ((size_t)b*DSN + n)*LL + l0);
  float h = 0.f, dtsum = 0.f;
  float4 dA_ = pdt[0], xA_ = pxi[0], bA_ = pB[0];
  #pragma unroll
  for (int g = 0; g < CL/4; ++g){
    float4 dB_, xB_, bB_;
    if (g + 1 < CL/4){ dB_ = pdt[g+1]; xB_ = pxi[g+1]; bB_ = pB[g+1]; }
    float dv[4] = {dA_.x, dA_.y, dA_.z, dA_.w};
    float xv[4] = {xA_.x, xA_.y, xA_.z, xA_.w};
    float bv[4] = {bA_.x, bA_.y, bA_.z, bA_.w};
    #pragma unroll
    for (int i = 0; i < 4; ++i){
      float e = __expf(dv[i]*A);
      h = e*h + (dv[i]*xv[i])*bv[i];
      dtsum += dv[i];
    }
    dA_ = dB_; xA_ = xB_; bA_ = bB_;
  }
  size_t idx = (((size_t)b*DI + d)*DSN + n)*NC + j;
  hend[idx]  = h;
  Pprod[idx] = __expf(A * dtsum);
}

// ---------------- 6b. carry scan across chunks (in-place: hend <- carry-in) ----------------
__global__ void carry_kernel(float* __restrict__ hend, const float* __restrict__ Pprod){
  int idx = blockIdx.x*256 + threadIdx.x;   // (b*DI+d)*DSN+n
  size_t base = (size_t)idx * NC;
  float c = 0.f;
  #pragma unroll
  for (int j = 0; j < NC; ++j){
    float he = hend[base + j];
    float P  = Pprod[base + j];
    hend[base + j] = c;       // carry-in for chunk j
    c = P * c + he;
  }
}

// ---------------- 6c. final scan per chunk: float4-streamed ----------------
__global__ __launch_bounds__(256) void scan_part2_kernel(const float* __restrict__ dtT,
    const float* __restrict__ xiT, const float* __restrict__ BT,
    const float* __restrict__ CT, const float* __restrict__ zbuf,
    const float* __restrict__ A_log, const float* __restrict__ Dp,
    const float* __restrict__ cin, float* __restrict__ ybuf){
  int t = threadIdx.x;
  int n = t & 15, dl = t >> 4;
  int d = blockIdx.y * 16 + dl;
  int b = blockIdx.x, j = blockIdx.z;
  float A = -__expf(A_log[d*DSN + n]);
  float Dd = Dp[d];
  float h = cin[(((size_t)b*DI + d)*DSN + n)*NC + j];
  int l0 = j * CL;
  const float4* pdt = (const float4*)(dtT + ((size_t)b*DI + d)*LL + l0);
  const float4* pxi = (const float4*)(xiT + ((size_t)b*DI + d)*LL + l0);
  const float4* pB  = (const float4*)(BT  + ((size_t)b*DSN + n)*LL + l0);
  const float4* pC  = (const float4*)(CT  + ((size_t)b*DSN + n)*LL + l0);
  const float* pz   = zbuf + ((size_t)b*LL + l0)*DI + d;   // stride DI per step
  float* py         = ybuf + ((size_t)b*LL + l0)*DI + d;

  float4 dA_ = pdt[0], xA_ = pxi[0], bA_ = pB[0], cA_ = pC[0];
  float zA_[4], zB_[4];
  #pragma unroll
  for (int i = 0; i < 4; ++i) zA_[i] = pz[i*DI];
  #pragma unroll
  for (int g = 0; g < CL/4; ++g){
    float4 dB_, xB_, bB_, cB_;
    if (g + 1 < CL/4){
      dB_ = pdt[g+1]; xB_ = pxi[g+1]; bB_ = pB[g+1]; cB_ = pC[g+1];
      #pragma unroll
      for (int i = 0; i < 4; ++i) zB_[i] = pz[(g*4 + 4 + i)*DI];
    }
    float dv[4] = {dA_.x, dA_.y, dA_.z, dA_.w};
    float xv[4] = {xA_.x, xA_.y, xA_.z, xA_.w};
    float bv[4] = {bA_.x, bA_.y, bA_.z, bA_.w};
    float cv[4] = {cA_.x, cA_.y, cA_.z, cA_.w};
    #pragma unroll
    for (int i = 0; i < 4; ++i){
      float e = __expf(dv[i]*A);
      h = e*h + (dv[i]*xv[i])*bv[i];
      float p = h * cv[i];
      p += __shfl_xor(p, 8, 16);
      p += __shfl_xor(p, 4, 16);
      p += __shfl_xor(p, 2, 16);
      p += __shfl_xor(p, 1, 16);
      if (n == 0) py[(g*4 + i)*DI] = (p + Dd*xv[i]) * zA_[i];
    }
    dA_ = dB_; xA_ = xB_; bA_ = bB_; cA_ = cB_;
    #pragma unroll
    for (int i = 0; i < 4; ++i) zA_[i] = zB_[i];
  }
}

// ---------------- 7. out_proj GEMM (64x128 tile) + fused outlayer/denorm/fc0 ----------------
__global__ __launch_bounds__(256) void gemm_out_kernel(const float* __restrict__ A,
    const float* __restrict__ W, const float* __restrict__ olw,
    const float* __restrict__ stats, const float* __restrict__ fc0w,
    const float* __restrict__ fc0b, float* __restrict__ h0){
  __shared__ float AsT[32][68];
  __shared__ float Bs[32][128];
  int tid = threadIdx.x;
  int tx = tid & 15, ty = tid >> 4;
  int rowBase = blockIdx.x * 64;
  float acc[4][8] = {};
  for (int kc = 0; kc < DI; kc += 32){
    #pragma unroll
    for (int i = 0; i < 8; ++i){
      int idx = tid + i*256;
      int r = idx >> 5, k = idx & 31;
      AsT[k][r] = A[(size_t)(rowBase + r)*DI + kc + k];
    }
    #pragma unroll
    for (int i = 0; i < 16; ++i){
      int idx = tid + i*256;
      int k = idx >> 7, c = idx & 127;
      Bs[k][c] = W[(size_t)(kc + k)*DM + c];
    }
    __syncthreads();
    #pragma unroll
    for (int k = 0; k < 32; ++k){
      float4 a  = *(const float4*)&AsT[k][ty*4];
      float4 b0 = *(const float4*)&Bs[k][tx*4];
      float4 b1 = *(const float4*)&Bs[k][64 + tx*4];
      float av[4] = {a.x, a.y, a.z, a.w};
      float b0v[4] = {b0.x, b0.y, b0.z, b0.w};
      float b1v[4] = {b1.x, b1.y, b1.z, b1.w};
      #pragma unroll
      for (int ii = 0; ii < 4; ++ii){
        #pragma unroll
        for (int jj = 0; jj < 4; ++jj){
          acc[ii][jj]     += av[ii]*b0v[jj];
          acc[ii][jj + 4] += av[ii]*b1v[jj];
        }
      }
    }
    __syncthreads();
  }
  float w0[4], w1[4];
  #pragma unroll
  for (int q = 0; q < 4; ++q){ w0[q] = olw[tx*4 + q]; w1[q] = olw[64 + tx*4 + q]; }
  int b = rowBase >> 9;
  float mean = stats[b], sd = stats[BB + b];
  float f0w = fc0w[0], f0b = fc0b[0];
  #pragma unroll
  for (int ii = 0; ii < 4; ++ii){
    float s = 0.f;
    #pragma unroll
    for (int q = 0; q < 4; ++q) s += acc[ii][q]*w0[q] + acc[ii][q + 4]*w1[q];
    s += __shfl_xor(s, 8, 16);
    s += __shfl_xor(s, 4, 16);
    s += __shfl_xor(s, 2, 16);
    s += __shfl_xor(s, 1, 16);
    if (tx == 0){
      float xo = s*sd + mean;
      float dec = fmaxf(xo, 0.f);
      h0[rowBase + ty*4 + ii] = fmaxf(dec*f0w + f0b, 0.f);
    }
  }
}

// ---------------- 9. final MLP per batch ----------------
__global__ __launch_bounds__(128) void mlp_kernel(const float* __restrict__ h0,
    const float* __restrict__ fc1w, const float* __restrict__ fc1b,
    const float* __restrict__ fc2w, const float* __restrict__ fc2b,
    const float* __restrict__ fc3w, const float* __restrict__ fc3b,
    float* __restrict__ out){
  __shared__ float h0s[LL];
  __shared__ float h1s[128];
  __shared__ float h2s[64];
  int b = blockIdx.x, t = threadIdx.x;
  #pragma unroll
  for (int i = 0; i < 4; ++i) h0s[t + i*128] = h0[b*LL + t + i*128];
  __syncthreads();
  float a = fc1b[t];
  for (int l = 0; l < LL; ++l) a += h0s[l] * fc1w[l*128 + t];
  h1s[t] = fmaxf(a, 0.f);
  __syncthreads();
  if (t < 64){
    float a2 = fc2b[t];
    #pragma unroll 4
    for (int k = 0; k < 128; ++k) a2 += h1s[k] * fc2w[k*64 + t];
    h2s[t] = fmaxf(a2, 0.f);
  }
  __syncthreads();
  if (t < 64){
    float p = h2s[t] * fc3w[t];
    #pragma unroll
    for (int off = 32; off; off >>= 1) p += __shfl_down(p, off);
    if (t == 0) out[b] = p + fc3b[0];
  }
}

extern "C" void kernel_launch(void* const* d_in, const int* in_sizes, int n_in,
                              void* d_out, int out_size, void* d_ws, size_t ws_size,
                              hipStream_t stream){
  const float* x_enc      = (const float*)d_in[0];
  const float* x_mark_enc = (const float*)d_in[1];
  const float* tok_w      = (const float*)d_in[4];
  const float* temp_w     = (const float*)d_in[5];
  const float* in_proj_w  = (const float*)d_in[6];
  const float* conv_w     = (const float*)d_in[7];
  const float* conv_b     = (const float*)d_in[8];
  const float* x_proj_w   = (const float*)d_in[9];
  const float* dt_w       = (const float*)d_in[10];
  const float* dt_b       = (const float*)d_in[11];
  const float* A_log      = (const float*)d_in[12];
  const float* Dp         = (const float*)d_in[13];
  const float* out_proj_w = (const float*)d_in[14];
  const float* out_lay_w  = (const float*)d_in[15];
  const float* fc0_w      = (const float*)d_in[16];
  const float* fc0_b      = (const float*)d_in[17];
  const float* fc1_w      = (const float*)d_in[18];
  const float* fc1_b      = (const float*)d_in[19];
  const float* fc2_w      = (const float*)d_in[20];
  const float* fc2_b      = (const float*)d_in[21];
  const float* fc3_w      = (const float*)d_in[22];
  const float* fc3_b      = (const float*)d_in[23];
  float* outp = (float*)d_out;

  float* ws = (float*)d_ws;
  const int M = BB*LL;
  float* xn     = ws;                                   // M
  float* stats  = xn + M;                               // 64
  float* xbuf   = stats + 64;                           // M*128 (8MB) -> hend after in_proj
  float* xi_raw = xbuf + (size_t)M*DM;                  // M*256 -> xiT after conv
  float* zbuf   = xi_raw + (size_t)M*DI;                // M*256 (alive through part2)
  float* xi2    = zbuf + (size_t)M*DI;                  // M*256 -> ybuf after dbl
  float* BT     = xi2 + (size_t)M*DI;                   // M*16
  float* CT     = BT + (size_t)M*16;                    // M*16
  float* dtT    = CT + (size_t)M*16;                    // M*256
  float* Pprod  = dtT + (size_t)M*DI;                   // M*128 (2M floats)
  float* h0     = Pprod + (size_t)M*DM;                 // M
  float* xiT    = xi_raw;                               // reuse (xi_raw dead after conv)
  float* ybuf   = xi2;                                  // reuse (xi2 dead after dbl)
  float* hend   = xbuf;                                 // reuse (xbuf dead after in_proj), 2M floats

  norm_kernel<<<BB, 256, 0, stream>>>(x_enc, xn, stats);
  embed_kernel<<<M, DM, 0, stream>>>(xn, x_mark_enc, tok_w, temp_w, xbuf);
  gemm64_kernel<1><<<dim3(M/64, 8), 256, 0, stream>>>(xbuf, in_proj_w, xi_raw, zbuf, M, 512, DM);
  conv_kernel<<<M, DI, 0, stream>>>(xi_raw, conv_w, conv_b, xi2);
  dbl_kernel<<<M/32, 256, 0, stream>>>(xi2, x_proj_w, dt_w, dt_b, BT, CT, dtT, xiT);
  scan_part1_kernel<<<dim3(BB, DI/16, NC), 256, 0, stream>>>(dtT, xiT, BT, A_log, hend, Pprod);
  carry_kernel<<<BB*DI*DSN/256, 256, 0, stream>>>(hend, Pprod);
  scan_part2_kernel<<<dim3(BB, DI/16, NC), 256, 0, stream>>>(dtT, xiT, BT, CT, zbuf, A_log, Dp, hend, ybuf);
  gemm_out_kernel<<<M/64, 256, 0, stream>>>(ybuf, out_proj_w, out_lay_w, stats, fc0_w, fc0_b, h0);
  mlp_kernel<<<BB, 128, 0, stream>>>(h0, fc1_w, fc1_b, fc2_w, fc2_b, fc3_w, fc3_b, outp);
}

// Round 8
// 200.591 us; speedup vs baseline: 1.5789x; 1.5789x over previous
//
#include <hip/hip_runtime.h>
#include <math.h>

#define BB 32
#define LL 512
#define DM 128
#define DI 256
#define DSN 16
#define NMK 4
#define NC 32
#define CL 16   // LL/NC

__device__ __forceinline__ float silu_f(float x){ return x / (1.f + __expf(-x)); }

// ---------------- 1. per-batch normalization ----------------
__global__ void norm_kernel(const float* __restrict__ x_enc,
                            float* __restrict__ xn, float* __restrict__ stats){
  __shared__ float xs[LL];
  __shared__ float red[256];
  int b = blockIdx.x, t = threadIdx.x;
  xs[t]       = x_enc[b*LL + t];
  xs[t + 256] = x_enc[b*LL + t + 256];
  __syncthreads();
  red[t] = xs[t] + xs[t + 256];
  __syncthreads();
  for (int s = 128; s; s >>= 1){ if (t < s) red[t] += red[t + s]; __syncthreads(); }
  float mean = red[0] / (float)LL;
  __syncthreads();
  float xc0 = xs[t] - mean, xc1 = xs[t + 256] - mean;
  red[t] = xc0*xc0 + xc1*xc1;
  __syncthreads();
  for (int s = 128; s; s >>= 1){ if (t < s) red[t] += red[t + s]; __syncthreads(); }
  float var = red[0] / (float)LL;
  float sd = sqrtf(var + 1e-5f);
  xn[b*LL + t]       = xc0 / sd;
  xn[b*LL + t + 256] = xc1 / sd;
  if (t == 0){ stats[b] = mean; stats[BB + b] = sd; }
}

// ---------------- 2. token conv + temporal + positional embedding ----------------
__global__ void embed_kernel(const float* __restrict__ xn, const float* __restrict__ xmark,
                             const float* __restrict__ tok_w, const float* __restrict__ temp_w,
                             float* __restrict__ xbuf){
  int row = blockIdx.x;          // b*LL + l
  int o = threadIdx.x;           // 0..127
  int b = row >> 9, l = row & 511;
  float xm1 = xn[b*LL + ((l == 0) ? (LL - 1) : (l - 1))];
  float x0  = xn[row];
  float xp1 = xn[b*LL + ((l == LL - 1) ? 0 : (l + 1))];
  float v = xm1 * tok_w[o*3 + 0] + x0 * tok_w[o*3 + 1] + xp1 * tok_w[o*3 + 2];
  #pragma unroll
  for (int m = 0; m < NMK; ++m) v += xmark[row*NMK + m] * temp_w[m*DM + o];
  int i = o >> 1;
  float ang = (float)l * expf((float)(2*i) * -0.07195578415606394f); // -ln(10000)/128
  v += (o & 1) ? cosf(ang) : sinf(ang);
  xbuf[row*DM + o] = v;
}

// ---------------- 3. in_proj GEMM 64x64 tile; epilogue splits xi / silu(z) ----------------
template<int MODE>
__global__ __launch_bounds__(256) void gemm64_kernel(const float* __restrict__ A,
    const float* __restrict__ W, float* __restrict__ out0, float* __restrict__ out1,
    int M, int N, int K){
  __shared__ float AsT[32][68];
  __shared__ float Bs[32][64];
  int tid = threadIdx.x;
  int tx = tid & 15, ty = tid >> 4;
  int rowBase = blockIdx.x * 64, colBase = blockIdx.y * 64;
  float acc[4][4] = {};
  for (int kc = 0; kc < K; kc += 32){
    #pragma unroll
    for (int i = 0; i < 8; ++i){
      int idx = tid + i*256;
      int r = idx >> 5, k = idx & 31;
      AsT[k][r] = A[(size_t)(rowBase + r)*K + kc + k];
    }
    #pragma unroll
    for (int i = 0; i < 8; ++i){
      int idx = tid + i*256;
      int k = idx >> 6, c = idx & 63;
      Bs[k][c] = W[(size_t)(kc + k)*N + colBase + c];
    }
    __syncthreads();
    #pragma unroll
    for (int k = 0; k < 32; ++k){
      float4 a  = *(const float4*)&AsT[k][ty*4];
      float4 bv = *(const float4*)&Bs[k][tx*4];
      float av[4] = {a.x, a.y, a.z, a.w};
      float bb[4] = {bv.x, bv.y, bv.z, bv.w};
      #pragma unroll
      for (int ii = 0; ii < 4; ++ii)
        #pragma unroll
        for (int jj = 0; jj < 4; ++jj) acc[ii][jj] += av[ii]*bb[jj];
    }
    __syncthreads();
  }
  #pragma unroll
  for (int ii = 0; ii < 4; ++ii){
    int row = rowBase + ty*4 + ii;
    #pragma unroll
    for (int jj = 0; jj < 4; ++jj){
      int col = colBase + tx*4 + jj;
      float v = acc[ii][jj];
      if (MODE == 0){
        out0[(size_t)row*N + col] = v;
      } else {
        if (col < DI) out0[(size_t)row*DI + col] = v;
        else          out1[(size_t)row*DI + col - DI] = silu_f(v);
      }
    }
  }
}

// ---------------- 4. depthwise causal conv + silu ----------------
__global__ void conv_kernel(const float* __restrict__ xi_raw, const float* __restrict__ conv_w,
                            const float* __restrict__ conv_b, float* __restrict__ xi2){
  int row = blockIdx.x, d = threadIdx.x;
  int l = row & 511;
  float acc = conv_b[d];
  #pragma unroll
  for (int k = 0; k < 4; ++k){
    int t = l + k - 3;
    if (t >= 0) acc += xi_raw[(size_t)(row + k - 3)*DI + d] * conv_w[d*4 + k];
  }
  xi2[(size_t)row*DI + d] = silu_f(acc);
}

// ---------------- 5. dbl GEMM (N=40) + fused dt projection/softplus ----------------
// 32-row tiles -> 512 blocks. Outputs Bpack/Cpack [row][16], dtpre [row][d].
__global__ __launch_bounds__(256) void dbl_kernel(const float* __restrict__ xi2,
    const float* __restrict__ xpw, const float* __restrict__ dt_w,
    const float* __restrict__ dt_b, float* __restrict__ Bpack,
    float* __restrict__ Cpack, float* __restrict__ dtpre){
  __shared__ float Xs[64][33];    // [k][row]
  __shared__ float Ws[64][48];    // [k][col], 40 padded to 48
  __shared__ float rowp8[32][8];
  int t = threadIdx.x;
  int r = t >> 3, g = t & 7;      // row 0..31, colgroup 0..7 (6 cols each)
  int rowBase = blockIdx.x * 32;
  float acc[6] = {};
  for (int kc = 0; kc < DI; kc += 64){
    #pragma unroll
    for (int i = 0; i < 8; ++i){
      int idx = t + i*256;
      int rr = idx >> 6, k = idx & 63;
      Xs[k][rr] = xi2[(size_t)(rowBase + rr)*DI + kc + k];
    }
    #pragma unroll
    for (int i = 0; i < 12; ++i){
      int idx = t + i*256;
      int k = idx / 48, j = idx % 48;
      Ws[k][j] = (j < 40) ? xpw[(kc + k)*40 + j] : 0.f;
    }
    __syncthreads();
    #pragma unroll 8
    for (int k = 0; k < 64; ++k){
      float a = Xs[k][r];
      const float2* wr = (const float2*)&Ws[k][g*6];
      float2 w0 = wr[0], w1 = wr[1], w2 = wr[2];
      acc[0] += a*w0.x; acc[1] += a*w0.y;
      acc[2] += a*w1.x; acc[3] += a*w1.y;
      acc[4] += a*w2.x; acc[5] += a*w2.y;
    }
    __syncthreads();
  }
  size_t row = rowBase + r;
  #pragma unroll
  for (int jj = 0; jj < 6; ++jj){
    int j = g*6 + jj;
    if (j < 8)             rowp8[r][j] = acc[jj];
    else if (j < 24)       Bpack[row*16 + (j - 8)]  = acc[jj];
    else if (j < 40)       Cpack[row*16 + (j - 24)] = acc[jj];
  }
  __syncthreads();
  // dt phase: thread t = channel d; 32 rows each
  float dtw_l[8];
  #pragma unroll
  for (int q = 0; q < 8; ++q) dtw_l[q] = dt_w[q*DI + t];
  float dtb_l = dt_b[t];
  for (int rr = 0; rr < 32; ++rr){
    float dtp = dtb_l;
    #pragma unroll
    for (int q = 0; q < 8; ++q) dtp += rowp8[rr][q] * dtw_l[q];
    float dt = fmaxf(dtp, 0.f) + log1pf(__expf(-fabsf(dtp)));
    dtpre[(size_t)(rowBase + rr)*DI + t] = dt;
  }
}

// ---------------- 6a. chunk scan, thread = d-channel, h[16] in registers ----------------
// grid (BB, NC), block 256 (= DI). Coalesced dt/xi; B tile staged in LDS.
__global__ __launch_bounds__(256) void scan_part1_kernel(const float* __restrict__ dtpre,
    const float* __restrict__ xi2, const float* __restrict__ Bpack,
    const float* __restrict__ A_log, float* __restrict__ hend, float* __restrict__ dtsum_g){
  __shared__ float Bs[CL*16];
  int d = threadIdx.x;
  int b = blockIdx.x, j = blockIdx.y;
  const size_t row0 = (size_t)b*LL + (size_t)j*CL;
  // stage B tile (CL*16 = 256 floats, 1 per thread)
  Bs[d] = Bpack[row0*16 + d];
  // A[16]
  float A[16];
  #pragma unroll
  for (int q = 0; q < 4; ++q){
    float4 a4 = *(const float4*)&A_log[d*DSN + q*4];
    A[q*4+0] = -__expf(a4.x); A[q*4+1] = -__expf(a4.y);
    A[q*4+2] = -__expf(a4.z); A[q*4+3] = -__expf(a4.w);
  }
  __syncthreads();
  const float* pdt = dtpre + row0*DI + d;
  const float* pxi = xi2   + row0*DI + d;
  float h[16];
  #pragma unroll
  for (int n = 0; n < 16; ++n) h[n] = 0.f;
  float dtsum = 0.f;
  float dtA[4], xiA[4], dtB[4], xiB[4];
  #pragma unroll
  for (int i = 0; i < 4; ++i){ dtA[i] = pdt[i*DI]; xiA[i] = pxi[i*DI]; }
  #pragma unroll
  for (int g = 0; g < CL/4; ++g){
    if (g + 1 < CL/4){
      #pragma unroll
      for (int i = 0; i < 4; ++i){ dtB[i] = pdt[(g*4+4+i)*DI]; xiB[i] = pxi[(g*4+4+i)*DI]; }
    }
    #pragma unroll
    for (int i = 0; i < 4; ++i){
      int l = g*4 + i;
      float dt = dtA[i], dtxi = dtA[i]*xiA[i];
      dtsum += dt;
      const float4* br = (const float4*)&Bs[l*16];
      float4 b0 = br[0], b1 = br[1], b2 = br[2], b3 = br[3];
      float bv[16] = {b0.x,b0.y,b0.z,b0.w, b1.x,b1.y,b1.z,b1.w,
                      b2.x,b2.y,b2.z,b2.w, b3.x,b3.y,b3.z,b3.w};
      #pragma unroll
      for (int n = 0; n < 16; ++n)
        h[n] = __expf(dt*A[n])*h[n] + dtxi*bv[n];
    }
    #pragma unroll
    for (int i = 0; i < 4; ++i){ dtA[i] = dtB[i]; xiA[i] = xiB[i]; }
  }
  // store h[16] (4x float4) and dtsum
  size_t o = ((size_t)(b*NC + j))*DI*DSN + (size_t)d*DSN;
  #pragma unroll
  for (int q = 0; q < 4; ++q){
    float4 v; v.x = h[q*4]; v.y = h[q*4+1]; v.z = h[q*4+2]; v.w = h[q*4+3];
    *(float4*)&hend[o + q*4] = v;
  }
  dtsum_g[(size_t)(b*NC + j)*DI + d] = dtsum;
}

// ---------------- 6b. carry scan across chunks (in-place: hend <- carry-in) ----------------
__global__ void carry_kernel(float* __restrict__ hend, const float* __restrict__ dtsum_g,
                             const float* __restrict__ A_log){
  int idx = blockIdx.x*256 + threadIdx.x;   // b*4096 + dn
  int b = idx >> 12, dn = idx & 4095;
  int d = dn >> 4;
  float A = -__expf(A_log[dn]);
  float c = 0.f;
  for (int j = 0; j < NC; ++j){
    size_t o = ((size_t)(b*NC + j))*4096 + dn;
    float he = hend[o];
    float P  = __expf(A * dtsum_g[(size_t)(b*NC + j)*DI + d]);
    hend[o] = c;
    c = P*c + he;
  }
}

// ---------------- 6c. final chunk scan from carry-in; y written in-place over z ----------------
__global__ __launch_bounds__(256) void scan_part2_kernel(const float* __restrict__ dtpre,
    const float* __restrict__ xi2, float* __restrict__ zy,
    const float* __restrict__ Bpack, const float* __restrict__ Cpack,
    const float* __restrict__ A_log, const float* __restrict__ Dp,
    const float* __restrict__ cin){
  __shared__ float Bs[CL*16];
  __shared__ float Cs[CL*16];
  int d = threadIdx.x;
  int b = blockIdx.x, j = blockIdx.y;
  const size_t row0 = (size_t)b*LL + (size_t)j*CL;
  Bs[d] = Bpack[row0*16 + d];
  Cs[d] = Cpack[row0*16 + d];
  float A[16];
  #pragma unroll
  for (int q = 0; q < 4; ++q){
    float4 a4 = *(const float4*)&A_log[d*DSN + q*4];
    A[q*4+0] = -__expf(a4.x); A[q*4+1] = -__expf(a4.y);
    A[q*4+2] = -__expf(a4.z); A[q*4+3] = -__expf(a4.w);
  }
  float h[16];
  size_t co = ((size_t)(b*NC + j))*DI*DSN + (size_t)d*DSN;
  #pragma unroll
  for (int q = 0; q < 4; ++q){
    float4 v = *(const float4*)&cin[co + q*4];
    h[q*4] = v.x; h[q*4+1] = v.y; h[q*4+2] = v.z; h[q*4+3] = v.w;
  }
  float Dd = Dp[d];
  __syncthreads();
  const float* pdt = dtpre + row0*DI + d;
  const float* pxi = xi2   + row0*DI + d;
  float* pz = zy + row0*DI + d;
  float dtA[4], xiA[4], zA[4], dtB[4], xiB[4], zB[4];
  #pragma unroll
  for (int i = 0; i < 4; ++i){ dtA[i] = pdt[i*DI]; xiA[i] = pxi[i*DI]; zA[i] = pz[i*DI]; }
  #pragma unroll
  for (int g = 0; g < CL/4; ++g){
    if (g + 1 < CL/4){
      #pragma unroll
      for (int i = 0; i < 4; ++i){
        dtB[i] = pdt[(g*4+4+i)*DI]; xiB[i] = pxi[(g*4+4+i)*DI]; zB[i] = pz[(g*4+4+i)*DI];
      }
    }
    #pragma unroll
    for (int i = 0; i < 4; ++i){
      int l = g*4 + i;
      float dt = dtA[i], xi = xiA[i];
      float dtxi = dt*xi;
      const float4* br = (const float4*)&Bs[l*16];
      const float4* cr = (const float4*)&Cs[l*16];
      float4 b0 = br[0], b1 = br[1], b2 = br[2], b3 = br[3];
      float4 c0 = cr[0], c1 = cr[1], c2 = cr[2], c3 = cr[3];
      float bv[16] = {b0.x,b0.y,b0.z,b0.w, b1.x,b1.y,b1.z,b1.w,
                      b2.x,b2.y,b2.z,b2.w, b3.x,b3.y,b3.z,b3.w};
      float cv[16] = {c0.x,c0.y,c0.z,c0.w, c1.x,c1.y,c1.z,c1.w,
                      c2.x,c2.y,c2.z,c2.w, c3.x,c3.y,c3.z,c3.w};
      float y = 0.f;
      #pragma unroll
      for (int n = 0; n < 16; ++n){
        h[n] = __expf(dt*A[n])*h[n] + dtxi*bv[n];
        y += h[n]*cv[n];
      }
      pz[l*DI] = (y + Dd*xi) * zA[i];
    }
    #pragma unroll
    for (int i = 0; i < 4; ++i){ dtA[i] = dtB[i]; xiA[i] = xiB[i]; zA[i] = zB[i]; }
  }
}

// ---------------- 7. out_proj GEMM (64x128 tile) + fused outlayer/denorm/fc0 ----------------
__global__ __launch_bounds__(256) void gemm_out_kernel(const float* __restrict__ A,
    const float* __restrict__ W, const float* __restrict__ olw,
    const float* __restrict__ stats, const float* __restrict__ fc0w,
    const float* __restrict__ fc0b, float* __restrict__ h0){
  __shared__ float AsT[32][68];
  __shared__ float Bs[32][128];
  int tid = threadIdx.x;
  int tx = tid & 15, ty = tid >> 4;
  int rowBase = blockIdx.x * 64;
  float acc[4][8] = {};
  for (int kc = 0; kc < DI; kc += 32){
    #pragma unroll
    for (int i = 0; i < 8; ++i){
      int idx = tid + i*256;
      int r = idx >> 5, k = idx & 31;
      AsT[k][r] = A[(size_t)(rowBase + r)*DI + kc + k];
    }
    #pragma unroll
    for (int i = 0; i < 16; ++i){
      int idx = tid + i*256;
      int k = idx >> 7, c = idx & 127;
      Bs[k][c] = W[(size_t)(kc + k)*DM + c];
    }
    __syncthreads();
    #pragma unroll
    for (int k = 0; k < 32; ++k){
      float4 a  = *(const float4*)&AsT[k][ty*4];
      float4 b0 = *(const float4*)&Bs[k][tx*4];
      float4 b1 = *(const float4*)&Bs[k][64 + tx*4];
      float av[4] = {a.x, a.y, a.z, a.w};
      float b0v[4] = {b0.x, b0.y, b0.z, b0.w};
      float b1v[4] = {b1.x, b1.y, b1.z, b1.w};
      #pragma unroll
      for (int ii = 0; ii < 4; ++ii){
        #pragma unroll
        for (int jj = 0; jj < 4; ++jj){
          acc[ii][jj]     += av[ii]*b0v[jj];
          acc[ii][jj + 4] += av[ii]*b1v[jj];
        }
      }
    }
    __syncthreads();
  }
  float w0[4], w1[4];
  #pragma unroll
  for (int q = 0; q < 4; ++q){ w0[q] = olw[tx*4 + q]; w1[q] = olw[64 + tx*4 + q]; }
  int b = rowBase >> 9;
  float mean = stats[b], sd = stats[BB + b];
  float f0w = fc0w[0], f0b = fc0b[0];
  #pragma unroll
  for (int ii = 0; ii < 4; ++ii){
    float s = 0.f;
    #pragma unroll
    for (int q = 0; q < 4; ++q) s += acc[ii][q]*w0[q] + acc[ii][q + 4]*w1[q];
    s += __shfl_xor(s, 8, 16);
    s += __shfl_xor(s, 4, 16);
    s += __shfl_xor(s, 2, 16);
    s += __shfl_xor(s, 1, 16);
    if (tx == 0){
      float xo = s*sd + mean;
      float dec = fmaxf(xo, 0.f);
      h0[rowBase + ty*4 + ii] = fmaxf(dec*f0w + f0b, 0.f);
    }
  }
}

// ---------------- 9. final MLP per batch ----------------
__global__ __launch_bounds__(128) void mlp_kernel(const float* __restrict__ h0,
    const float* __restrict__ fc1w, const float* __restrict__ fc1b,
    const float* __restrict__ fc2w, const float* __restrict__ fc2b,
    const float* __restrict__ fc3w, const float* __restrict__ fc3b,
    float* __restrict__ out){
  __shared__ float h0s[LL];
  __shared__ float h1s[128];
  __shared__ float h2s[64];
  int b = blockIdx.x, t = threadIdx.x;
  #pragma unroll
  for (int i = 0; i < 4; ++i) h0s[t + i*128] = h0[b*LL + t + i*128];
  __syncthreads();
  float a = fc1b[t];
  for (int l = 0; l < LL; ++l) a += h0s[l] * fc1w[l*128 + t];
  h1s[t] = fmaxf(a, 0.f);
  __syncthreads();
  if (t < 64){
    float a2 = fc2b[t];
    #pragma unroll 4
    for (int k = 0; k < 128; ++k) a2 += h1s[k] * fc2w[k*64 + t];
    h2s[t] = fmaxf(a2, 0.f);
  }
  __syncthreads();
  if (t < 64){
    float p = h2s[t] * fc3w[t];
    #pragma unroll
    for (int off = 32; off; off >>= 1) p += __shfl_down(p, off);
    if (t == 0) out[b] = p + fc3b[0];
  }
}

extern "C" void kernel_launch(void* const* d_in, const int* in_sizes, int n_in,
                              void* d_out, int out_size, void* d_ws, size_t ws_size,
                              hipStream_t stream){
  const float* x_enc      = (const float*)d_in[0];
  const float* x_mark_enc = (const float*)d_in[1];
  const float* tok_w      = (const float*)d_in[4];
  const float* temp_w     = (const float*)d_in[5];
  const float* in_proj_w  = (const float*)d_in[6];
  const float* conv_w     = (const float*)d_in[7];
  const float* conv_b     = (const float*)d_in[8];
  const float* x_proj_w   = (const float*)d_in[9];
  const float* dt_w       = (const float*)d_in[10];
  const float* dt_b       = (const float*)d_in[11];
  const float* A_log      = (const float*)d_in[12];
  const float* Dp         = (const float*)d_in[13];
  const float* out_proj_w = (const float*)d_in[14];
  const float* out_lay_w  = (const float*)d_in[15];
  const float* fc0_w      = (const float*)d_in[16];
  const float* fc0_b      = (const float*)d_in[17];
  const float* fc1_w      = (const float*)d_in[18];
  const float* fc1_b      = (const float*)d_in[19];
  const float* fc2_w      = (const float*)d_in[20];
  const float* fc2_b      = (const float*)d_in[21];
  const float* fc3_w      = (const float*)d_in[22];
  const float* fc3_b      = (const float*)d_in[23];
  float* outp = (float*)d_out;

  float* ws = (float*)d_ws;
  const int M = BB*LL;
  float* xn     = ws;                                   // M
  float* stats  = xn + M;                               // 64
  float* xbuf   = stats + 64;                           // M*128 (dead after in_proj)
  float* xi_raw = xbuf + (size_t)M*DM;                  // M*256 (dead after conv -> hend)
  float* zbuf   = xi_raw + (size_t)M*DI;                // M*256 (y written in-place)
  float* xi2    = zbuf + (size_t)M*DI;                  // M*256
  float* Bpack  = xi2 + (size_t)M*DI;                   // M*16
  float* Cpack  = Bpack + (size_t)M*16;                 // M*16
  float* dtpre  = Cpack + (size_t)M*16;                 // M*256
  float* h0     = dtpre + (size_t)M*DI;                 // M
  float* dtsum  = h0 + M;                               // BB*NC*DI = M*16
  float* hend   = xi_raw;                               // reuse: BB*NC*DI*DSN = M*256

  norm_kernel<<<BB, 256, 0, stream>>>(x_enc, xn, stats);
  embed_kernel<<<M, DM, 0, stream>>>(xn, x_mark_enc, tok_w, temp_w, xbuf);
  gemm64_kernel<1><<<dim3(M/64, 8), 256, 0, stream>>>(xbuf, in_proj_w, xi_raw, zbuf, M, 512, DM);
  conv_kernel<<<M, DI, 0, stream>>>(xi_raw, conv_w, conv_b, xi2);
  dbl_kernel<<<M/32, 256, 0, stream>>>(xi2, x_proj_w, dt_w, dt_b, Bpack, Cpack, dtpre);
  scan_part1_kernel<<<dim3(BB, NC), 256, 0, stream>>>(dtpre, xi2, Bpack, A_log, hend, dtsum);
  carry_kernel<<<BB*DI*DSN/256, 256, 0, stream>>>(hend, dtsum, A_log);
  scan_part2_kernel<<<dim3(BB, NC), 256, 0, stream>>>(dtpre, xi2, zbuf, Bpack, Cpack, A_log, Dp, hend);
  gemm_out_kernel<<<M/64, 256, 0, stream>>>(zbuf, out_proj_w, out_lay_w, stats, fc0_w, fc0_b, h0);
  mlp_kernel<<<BB, 128, 0, stream>>>(h0, fc1_w, fc1_b, fc2_w, fc2_b, fc3_w, fc3_b, outp);
}